// Round 1
// baseline (196.499 us; speedup 1.0000x reference)
//
#include <hip/hip_runtime.h>
#include <math.h>

#define NROW 16384
#define DIM 2048
#define NLAB 20
#define T_INV 10.0f
#define PD_EPS 1e-6f
#define NORM_EPS 1e-12f

#define MAIN_BLOCKS 1024
#define THREADS 256
// ws float layout: [0..2047] = a vector, [2048] = S_aa, [2560 ..] = block partials (3 per block)
#define WS_PARTIALS_OFS 2560

// Kernel 1: one block. Compute a = embed_row0 / max(||row0||,eps) + PD_EPS, and S_aa = sum(a^2).
__global__ __launch_bounds__(THREADS) void prep_kernel(const float* __restrict__ embed,
                                                       float* __restrict__ ws) {
    __shared__ float red[THREADS / 64];
    const int tid = threadIdx.x;
    const int lane = tid & 63, wid = tid >> 6;

    const float4* row0 = (const float4*)embed;
    float s = 0.f;
    for (int i = tid; i < DIM / 4; i += THREADS) {
        float4 v = row0[i];
        s += v.x * v.x + v.y * v.y + v.z * v.z + v.w * v.w;
    }
    for (int o = 32; o; o >>= 1) s += __shfl_xor(s, o, 64);
    if (lane == 0) red[wid] = s;
    __syncthreads();
    float tot = red[0] + red[1] + red[2] + red[3];
    float inv = 1.0f / fmaxf(sqrtf(tot), NORM_EPS);

    float saa = 0.f;
    float4* a4 = (float4*)ws;
    for (int i = tid; i < DIM / 4; i += THREADS) {
        float4 v = row0[i];
        float4 w;
        w.x = v.x * inv + PD_EPS;
        w.y = v.y * inv + PD_EPS;
        w.z = v.z * inv + PD_EPS;
        w.w = v.w * inv + PD_EPS;
        a4[i] = w;
        saa += w.x * w.x + w.y * w.y + w.z * w.z + w.w * w.w;
    }
    for (int o = 32; o; o >>= 1) saa += __shfl_xor(saa, o, 64);
    __syncthreads();
    if (lane == 0) red[wid] = saa;
    __syncthreads();
    if (tid == 0) ws[DIM] = red[0] + red[1] + red[2] + red[3];
}

// Kernel 2: one row per wave per grid-stride step. Single pass over embed rows 1..NROW-1.
__global__ __launch_bounds__(THREADS) void main_kernel(const float* __restrict__ embed,
                                                       const int* __restrict__ labels,
                                                       const float* __restrict__ ws) {
    __shared__ float a_lds[DIM];
    __shared__ float wsum[THREADS / 64][3];

    const int tid = threadIdx.x;
    const int lane = tid & 63, wid = tid >> 6;

    // stage a[] into LDS (8 KB), coalesced float4
    {
        const float4* src = (const float4*)ws;
        float4* dst = (float4*)a_lds;
        for (int i = tid; i < DIM / 4; i += THREADS) dst[i] = src[i];
    }
    const float S_aa = ws[DIM];
    __syncthreads();

    const float lab0 = (lane < NLAB) ? (float)labels[lane] : 0.f;

    const int gw = blockIdx.x * (THREADS / 64) + wid;   // global wave id
    const int nwaves = gridDim.x * (THREADS / 64);

    float acc_e = 0.f, acc_c = 0.f, acc_cl = 0.f;

    for (int row = 1 + gw; row < NROW; row += nwaves) {
        const float4* b4 = (const float4*)(embed + (size_t)row * DIM);
        const float4* a4 = (const float4*)a_lds;
        float sab = 0.f, sbb = 0.f;
#pragma unroll
        for (int it = 0; it < DIM / 4 / 64; ++it) {
            float4 bv = b4[it * 64 + lane];
            float4 av = a4[it * 64 + lane];
            sab += av.x * bv.x + av.y * bv.y + av.z * bv.z + av.w * bv.w;
            sbb += bv.x * bv.x + bv.y * bv.y + bv.z * bv.z + bv.w * bv.w;
        }
        float c = (lane < NLAB) ? lab0 * (float)labels[row * NLAB + lane] : 0.f;

        for (int o = 32; o; o >>= 1) {
            sab += __shfl_xor(sab, o, 64);
            sbb += __shfl_xor(sbb, o, 64);
            c   += __shfl_xor(c,   o, 64);
        }
        // all lanes now hold identical full sums
        float inv = 1.0f / fmaxf(sqrtf(sbb), NORM_EPS);
        float d2 = S_aa + inv * (inv * sbb - 2.0f * sab);
        d2 = fmaxf(d2, 0.f);
        float ls = -sqrtf(d2) * T_INV;   // log_sim = -d/T
        acc_e += expf(ls);
        acc_c += c;
        acc_cl += c * ls;
    }

    if (lane == 0) {
        wsum[wid][0] = acc_e;
        wsum[wid][1] = acc_c;
        wsum[wid][2] = acc_cl;
    }
    __syncthreads();
    if (tid == 0) {
        float se = 0.f, sc = 0.f, scl = 0.f;
        for (int w = 0; w < THREADS / 64; ++w) {
            se += wsum[w][0];
            sc += wsum[w][1];
            scl += wsum[w][2];
        }
        float* p = (float*)wsum;  // reuse nothing; write to global
        (void)p;
        float* partials = (float*)0;
        (void)partials;
        // global partials live in ws
        ((float*)ws)[0] = ((float*)ws)[0]; // no-op to keep ws const-cast away
        // NOTE: actual write below via separate pointer param-free cast:
        // we write through a non-const alias computed from ws base.
        float* wsw = const_cast<float*>(ws);
        wsw[WS_PARTIALS_OFS + blockIdx.x * 3 + 0] = se;
        wsw[WS_PARTIALS_OFS + blockIdx.x * 3 + 1] = sc;
        wsw[WS_PARTIALS_OFS + blockIdx.x * 3 + 2] = scl;
    }
}

// Kernel 3: one block folds MAIN_BLOCKS partials -> final scalar.
__global__ __launch_bounds__(THREADS) void final_kernel(const float* __restrict__ ws,
                                                        float* __restrict__ out) {
    __shared__ float red[THREADS / 64][3];
    const int tid = threadIdx.x;
    const int lane = tid & 63, wid = tid >> 6;

    float se = 0.f, sc = 0.f, scl = 0.f;
    for (int i = tid; i < MAIN_BLOCKS; i += THREADS) {
        se  += ws[WS_PARTIALS_OFS + i * 3 + 0];
        sc  += ws[WS_PARTIALS_OFS + i * 3 + 1];
        scl += ws[WS_PARTIALS_OFS + i * 3 + 2];
    }
    for (int o = 32; o; o >>= 1) {
        se  += __shfl_xor(se,  o, 64);
        sc  += __shfl_xor(sc,  o, 64);
        scl += __shfl_xor(scl, o, 64);
    }
    if (lane == 0) { red[wid][0] = se; red[wid][1] = sc; red[wid][2] = scl; }
    __syncthreads();
    if (tid == 0) {
        se = sc = scl = 0.f;
        for (int w = 0; w < THREADS / 64; ++w) {
            se += red[w][0]; sc += red[w][1]; scl += red[w][2];
        }
        float Ci = 1e-12f + sc;
        float Ei = 1e-12f + se;
        float Li = (sc * logf(Ei) - scl) / Ci;
        out[0] = Li / (float)NROW;
    }
}

extern "C" void kernel_launch(void* const* d_in, const int* in_sizes, int n_in,
                              void* d_out, int out_size, void* d_ws, size_t ws_size,
                              hipStream_t stream) {
    const float* embed = (const float*)d_in[0];
    const int* labels = (const int*)d_in[1];
    float* out = (float*)d_out;
    float* ws = (float*)d_ws;

    prep_kernel<<<1, THREADS, 0, stream>>>(embed, ws);
    main_kernel<<<MAIN_BLOCKS, THREADS, 0, stream>>>(embed, labels, ws);
    final_kernel<<<1, THREADS, 0, stream>>>(ws, out);
}